// Round 5
// baseline (477.740 us; speedup 1.0000x reference)
//
#include <hip/hip_runtime.h>
#include <hip/hip_bf16.h>
#include <math.h>

#define B_   16
#define LQ_  2048
#define LK_  2048
#define D_   128
#define LN_EPS 1e-5f
#define NTILE (LK_ / 64)

typedef __attribute__((ext_vector_type(8))) short short8;
typedef __attribute__((ext_vector_type(4))) float f32x4;

union FragU { uint4 u4; short8 s8; unsigned int u[4]; };

__device__ __forceinline__ unsigned int pk_bf16(float a, float b) {
  __hip_bfloat162 h = __float22bfloat162_rn(make_float2(a, b));
  unsigned int u;
  __builtin_memcpy(&u, &h, 4);
  return u;
}
__device__ __forceinline__ float bf_lo(unsigned int u){ unsigned int v = u << 16; float f; __builtin_memcpy(&f, &v, 4); return f; }
__device__ __forceinline__ float bf_hi(unsigned int u){ unsigned int v = u & 0xffff0000u; float f; __builtin_memcpy(&f, &v, 4); return f; }
__device__ __forceinline__ unsigned short bf16_bits(float x) {
  return (unsigned short)(pk_bf16(x, 0.f) & 0xffffu);
}

// K tiles: ushort [64 rows][128 d], 16B(8-ushort)-chunk XOR swizzle by row.
__device__ __forceinline__ int idxK(int row, int d) {
  return row * 128 + ((((d >> 3) ^ row) & 15) << 3) + (d & 7);
}
// Vt: uint words [128 d][32 kv-pairs]; 16B(4-word)-chunk swizzle by h(d).
__device__ __forceinline__ int idxVt(int d, int kp) {
  int h = ((d >> 2) ^ ((d & 3) << 1)) & 7;
  return d * 32 + ((((kp >> 2) ^ h) & 7) << 2) + (kp & 3);
}
// Ps: ushort [4 waves][32 rows][32 cols], 8-ushort-chunk swizzle by row[3:0].
__device__ __forceinline__ int idxPs(int w, int row, int col) {
  int s = ((col >> 3) ^ (row & 3) ^ ((row >> 2) & 3)) & 3;
  return (w * 32 + row) * 32 + (s << 3) + (col & 7);
}

// LDS-only barrier: drains ds ops, leaves global (vmcnt) loads in flight.
__device__ __forceinline__ void barrier_lds() {
  asm volatile("s_waitcnt lgkmcnt(0)\n\ts_barrier" ::: "memory");
}

__global__ __launch_bounds__(256, 2) void attn_ln_mfma(
    const float* __restrict__ qg, const float* __restrict__ kg,
    const float* __restrict__ vg, const float* __restrict__ maskg,
    const float* __restrict__ gammag, const float* __restrict__ betag,
    float* __restrict__ outg)
{
  // 56 KB, aliased: loop layout = Kh(16K) Kl(16K) Vt(16K) Ps(8K);
  // epilogue layout = O-exchange(32K) l-exchange(4K)
  __shared__ __align__(16) unsigned char smem[57344];
  unsigned short* KhS = (unsigned short*)(smem);
  unsigned short* KlS = (unsigned short*)(smem + 16384);
  unsigned int*   VtW = (unsigned int*)  (smem + 32768);
  unsigned short* PsS = (unsigned short*)(smem + 49152);

  const int tid  = threadIdx.x;
  const int w    = tid >> 6;        // wave 0..3
  const int lane = tid & 63;
  const int quad = lane >> 4;
  const int lr   = lane & 15;
  const int rowhalf = w & 1;        // q-rows (rowhalf*32 .. +32)
  const int khalf   = w >> 1;       // k-cols (khalf*32 .. +32) of each tile

  // XCD swizzle: blocks on XCD x serve batches {2x,2x+1} -> K/V L2-resident.
  const int id   = blockIdx.x;
  const int xcd  = id & 7;
  const int slot = id >> 3;
  const int b    = xcd * 2 + (slot >> 5);
  const int q0   = (slot & 31) * 64;

  // staging thread maps
  const int c8 = tid & 15, kr = tid >> 4;   // K: d0=c8*8, rows kr+16i
  const int vc = tid & 31, vr = tid >> 5;   // V: d0=vc*4, kp=vr+8j

  const float* gk = kg + (size_t)b * LK_ * D_;
  const float* gv = vg + (size_t)b * LK_ * D_;

  // ---- prefetch tile 0 (K rows + V row-pairs) ----
  float4 kpre[4][2], vpre[4][2];
#pragma unroll
  for (int i = 0; i < 4; i++) {
    const float* p = gk + (size_t)(kr + 16 * i) * D_ + c8 * 8;
    kpre[i][0] = *(const float4*)(p);
    kpre[i][1] = *(const float4*)(p + 4);
  }
#pragma unroll
  for (int j = 0; j < 4; j++) {
    const int kp = vr + 8 * j;
    vpre[j][0] = *(const float4*)(gv + (size_t)(2 * kp) * D_ + vc * 4);
    vpre[j][1] = *(const float4*)(gv + (size_t)(2 * kp + 1) * D_ + vc * 4);
  }

  // ---- Q fragments (hi/lo) for 2 row-tiles (32 rows/wave) ----
  short8 qh[2][4], ql[2][4];
#pragma unroll
  for (int rt = 0; rt < 2; rt++) {
    const float* qrow = qg + ((size_t)b * LQ_ + q0 + rowhalf * 32 + rt * 16 + lr) * D_ + quad * 8;
#pragma unroll
    for (int c = 0; c < 4; c++) {
      float4 x = *(const float4*)(qrow + c * 32);
      float4 y = *(const float4*)(qrow + c * 32 + 4);
      FragU H, L;
      H.u[0] = pk_bf16(x.x, x.y); H.u[1] = pk_bf16(x.z, x.w);
      H.u[2] = pk_bf16(y.x, y.y); H.u[3] = pk_bf16(y.z, y.w);
      L.u[0] = pk_bf16(x.x - bf_lo(H.u[0]), x.y - bf_hi(H.u[0]));
      L.u[1] = pk_bf16(x.z - bf_lo(H.u[1]), x.w - bf_hi(H.u[1]));
      L.u[2] = pk_bf16(y.x - bf_lo(H.u[2]), y.y - bf_hi(H.u[2]));
      L.u[3] = pk_bf16(y.z - bf_lo(H.u[3]), y.w - bf_hi(H.u[3]));
      qh[rt][c] = H.s8; ql[rt][c] = L.s8;
    }
  }

  float l_part[2][4];
  f32x4 o[2][8];
  const f32x4 zf = {0.f, 0.f, 0.f, 0.f};
#pragma unroll
  for (int rt = 0; rt < 2; rt++) {
#pragma unroll
    for (int r = 0; r < 4; r++) l_part[rt][r] = 0.f;
#pragma unroll
    for (int n = 0; n < 8; n++) o[rt][n] = zf;
  }

  for (int kt = 0; kt < NTILE; kt++) {
    const int k0 = kt * 64;
    barrier_lds();   // all waves done reading previous tile's LDS

    // ---- stage K (hi/lo bf16), b128 writes ----
#pragma unroll
    for (int i = 0; i < 4; i++) {
      const int row = kr + 16 * i;
      float4 x = kpre[i][0], y = kpre[i][1];
      FragU H, L;
      H.u[0] = pk_bf16(x.x, x.y); H.u[1] = pk_bf16(x.z, x.w);
      H.u[2] = pk_bf16(y.x, y.y); H.u[3] = pk_bf16(y.z, y.w);
      L.u[0] = pk_bf16(x.x - bf_lo(H.u[0]), x.y - bf_hi(H.u[0]));
      L.u[1] = pk_bf16(x.z - bf_lo(H.u[1]), x.w - bf_hi(H.u[1]));
      L.u[2] = pk_bf16(y.x - bf_lo(H.u[2]), y.y - bf_hi(H.u[2]));
      L.u[3] = pk_bf16(y.z - bf_lo(H.u[3]), y.w - bf_hi(H.u[3]));
      const int ik = idxK(row, c8 * 8);
      *(uint4*)&KhS[ik] = H.u4;
      *(uint4*)&KlS[ik] = L.u4;
    }

    // ---- stage V^T as bf16 kv-pairs (b32 writes) ----
#pragma unroll
    for (int j = 0; j < 4; j++) {
      const int kp = vr + 8 * j;
      float4 a = vpre[j][0], bb = vpre[j][1];
      VtW[idxVt(vc * 4 + 0, kp)] = pk_bf16(a.x, bb.x);
      VtW[idxVt(vc * 4 + 1, kp)] = pk_bf16(a.y, bb.y);
      VtW[idxVt(vc * 4 + 2, kp)] = pk_bf16(a.z, bb.z);
      VtW[idxVt(vc * 4 + 3, kp)] = pk_bf16(a.w, bb.w);
    }

    // ---- mask loads (this wave's 32 rows x 32 cols) ----
    float mkv[2][2][4];
#pragma unroll
    for (int rt = 0; rt < 2; rt++)
#pragma unroll
      for (int t = 0; t < 2; t++)
#pragma unroll
        for (int reg = 0; reg < 4; reg++)
          mkv[rt][t][reg] = maskg[(size_t)(q0 + rowhalf * 32 + rt * 16 + quad * 4 + reg) * LK_
                                  + k0 + khalf * 32 + t * 16 + lr];

    // ---- prefetch NEXT tile (in flight across the raw barrier) ----
    if (kt + 1 < NTILE) {
#pragma unroll
      for (int i = 0; i < 4; i++) {
        const float* p = gk + (size_t)(k0 + 64 + kr + 16 * i) * D_ + c8 * 8;
        kpre[i][0] = *(const float4*)(p);
        kpre[i][1] = *(const float4*)(p + 4);
      }
#pragma unroll
      for (int j = 0; j < 4; j++) {
        const int kp = vr + 8 * j;
        vpre[j][0] = *(const float4*)(gv + (size_t)(k0 + 64 + 2 * kp) * D_ + vc * 4);
        vpre[j][1] = *(const float4*)(gv + (size_t)(k0 + 64 + 2 * kp + 1) * D_ + vc * 4);
      }
    }

    barrier_lds();   // staged tile visible

    // ---- S = Q K^T via MFMA (hi/lo); this wave's 32 k-cols only ----
    f32x4 sacc[2][2];
#pragma unroll
    for (int rt = 0; rt < 2; rt++)
#pragma unroll
      for (int t = 0; t < 2; t++) sacc[rt][t] = zf;
#pragma unroll
    for (int c = 0; c < 4; c++) {
      const int kb = c * 32 + quad * 8;
#pragma unroll
      for (int t = 0; t < 2; t++) {
        const int krow = khalf * 32 + t * 16 + lr;
        FragU kh, kl;
        kh.u4 = *(const uint4*)&KhS[idxK(krow, kb)];
        kl.u4 = *(const uint4*)&KlS[idxK(krow, kb)];
#pragma unroll
        for (int rt = 0; rt < 2; rt++) {
          sacc[rt][t] = __builtin_amdgcn_mfma_f32_16x16x32_bf16(qh[rt][c], kh.s8, sacc[rt][t], 0, 0, 0);
          sacc[rt][t] = __builtin_amdgcn_mfma_f32_16x16x32_bf16(ql[rt][c], kh.s8, sacc[rt][t], 0, 0, 0);
          sacc[rt][t] = __builtin_amdgcn_mfma_f32_16x16x32_bf16(qh[rt][c], kl.s8, sacc[rt][t], 0, 0, 0);
        }
      }
    }

    // ---- max-free softmax; P -> per-wave LDS as bf16 ----
#pragma unroll
    for (int rt = 0; rt < 2; rt++)
#pragma unroll
      for (int reg = 0; reg < 4; reg++) {
        const int prow = rt * 16 + quad * 4 + reg;
        float p0 = __expf(sacc[rt][0][reg] + mkv[rt][0][reg]);
        float p1 = __expf(sacc[rt][1][reg] + mkv[rt][1][reg]);
        l_part[rt][reg] += p0 + p1;
        PsS[idxPs(w, prow, lr)]      = bf16_bits(p0);
        PsS[idxPs(w, prow, 16 + lr)] = bf16_bits(p1);
      }

    asm volatile("s_waitcnt lgkmcnt(0)" ::: "memory");  // own Ps visible (per-wave region)

    // ---- O += P * V via MFMA (one k-step of 32 per row-tile) ----
    FragU pa0, pa1;
    pa0.u4 = *(const uint4*)&PsS[idxPs(w, lr,      quad * 8)];
    pa1.u4 = *(const uint4*)&PsS[idxPs(w, 16 + lr, quad * 8)];
#pragma unroll
    for (int n = 0; n < 8; n++) {
      FragU Bv;
      Bv.u4 = *(const uint4*)&VtW[idxVt(n * 16 + lr, khalf * 16 + quad * 4)];
      o[0][n] = __builtin_amdgcn_mfma_f32_16x16x32_bf16(pa0.s8, Bv.s8, o[0][n], 0, 0, 0);
      o[1][n] = __builtin_amdgcn_mfma_f32_16x16x32_bf16(pa1.s8, Bv.s8, o[1][n], 0, 0, 0);
    }
  }

  // ---- epilogue: combine k-halves across wave pairs, LayerNorm, store ----
  barrier_lds();   // loop LDS reads drained; safe to alias smem

  float* exO = (float*)smem;            // 32 KB: [rowhalf][lane][64 floats]
  float* exL = (float*)(smem + 32768);  // 4 KB:  [rowhalf][lane][8 floats]

  if (khalf) {
    float* myO = exO + rowhalf * 4096 + lane * 64;
#pragma unroll
    for (int rt = 0; rt < 2; rt++)
#pragma unroll
      for (int n = 0; n < 8; n++) {
        const int c = rt * 8 + n;
        *(f32x4*)(myO + ((c ^ (lane & 15)) & 15) * 4) = o[rt][n];
      }
    float* myL = exL + rowhalf * 512 + lane * 8;
    f32x4 l0 = {l_part[0][0], l_part[0][1], l_part[0][2], l_part[0][3]};
    f32x4 l1 = {l_part[1][0], l_part[1][1], l_part[1][2], l_part[1][3]};
    *(f32x4*)(myL)     = l0;
    *(f32x4*)(myL + 4) = l1;
  }

  barrier_lds();   // partner data visible

  if (!khalf) {
    float* pO = exO + rowhalf * 4096 + lane * 64;
#pragma unroll
    for (int rt = 0; rt < 2; rt++)
#pragma unroll
      for (int n = 0; n < 8; n++) {
        const int c = rt * 8 + n;
        f32x4 t = *(const f32x4*)(pO + ((c ^ (lane & 15)) & 15) * 4);
        o[rt][n] += t;
      }
    float* pL = exL + rowhalf * 512 + lane * 8;
    f32x4 l0 = *(const f32x4*)(pL);
    f32x4 l1 = *(const f32x4*)(pL + 4);
#pragma unroll
    for (int r = 0; r < 4; r++) { l_part[0][r] += l0[r]; l_part[1][r] += l1[r]; }

    float gam[8], bet[8];
#pragma unroll
    for (int n = 0; n < 8; n++) {
      gam[n] = gammag[n * 16 + lr];
      bet[n] = betag[n * 16 + lr];
    }

#pragma unroll
    for (int rt = 0; rt < 2; rt++)
#pragma unroll
      for (int reg = 0; reg < 4; reg++) {
        float l = l_part[rt][reg];
#pragma unroll
        for (int m = 1; m <= 8; m <<= 1) l += __shfl_xor(l, m, 64);
        const float inv_l = 1.f / l;

        float vals[8];
        float s1 = 0.f, s2 = 0.f;
#pragma unroll
        for (int n = 0; n < 8; n++) {
          vals[n] = o[rt][n][reg] * inv_l;
          s1 += vals[n]; s2 += vals[n] * vals[n];
        }
#pragma unroll
        for (int m = 1; m <= 8; m <<= 1) {
          s1 += __shfl_xor(s1, m, 64);
          s2 += __shfl_xor(s2, m, 64);
        }
        const float mean = s1 * (1.f / 128.f);
        const float var  = s2 * (1.f / 128.f) - mean * mean;
        const float rstd = rsqrtf(var + LN_EPS);

        float* op = outg + ((size_t)b * LQ_ + q0 + rowhalf * 32 + rt * 16 + quad * 4 + reg) * D_ + lr;
#pragma unroll
        for (int n = 0; n < 8; n++)
          op[n * 16] = (vals[n] - mean) * rstd * gam[n] + bet[n];
      }
  }
}

extern "C" void kernel_launch(void* const* d_in, const int* in_sizes, int n_in,
                              void* d_out, int out_size, void* d_ws, size_t ws_size,
                              hipStream_t stream) {
  const float* q     = (const float*)d_in[0];
  const float* k     = (const float*)d_in[1];
  const float* v     = (const float*)d_in[2];
  const float* mask  = (const float*)d_in[3];
  const float* gamma = (const float*)d_in[4];
  const float* beta  = (const float*)d_in[5];
  float* out = (float*)d_out;

  attn_ln_mfma<<<dim3(512), dim3(256), 0, stream>>>(q, k, v, mask, gamma, beta, out);
}

// Round 6
// 222.709 us; speedup vs baseline: 2.1451x; 2.1451x over previous
//
#include <hip/hip_runtime.h>
#include <hip/hip_bf16.h>
#include <math.h>

#define LQ_  2048
#define LK_  2048
#define D_   128
#define LN_EPS 1e-5f
#define TK_  32
#define NTILE (LK_ / TK_)

typedef __attribute__((ext_vector_type(8))) short short8;
typedef __attribute__((ext_vector_type(4))) float f32x4;

union FragU { uint4 u4; short8 s8; unsigned int u[4]; };

__device__ __forceinline__ unsigned int pk_bf16(float a, float b) {
  __hip_bfloat162 h = __float22bfloat162_rn(make_float2(a, b));
  unsigned int u;
  __builtin_memcpy(&u, &h, 4);
  return u;
}
__device__ __forceinline__ float bf_lo(unsigned int u){ unsigned int v = u << 16; float f; __builtin_memcpy(&f, &v, 4); return f; }
__device__ __forceinline__ float bf_hi(unsigned int u){ unsigned int v = u & 0xffff0000u; float f; __builtin_memcpy(&f, &v, 4); return f; }
__device__ __forceinline__ unsigned short bf16_bits(float x) {
  return (unsigned short)(pk_bf16(x, 0.f) & 0xffffu);
}

// K tiles: ushort [32 rows][128 d], 16B(8-ushort)-chunk XOR swizzle by row.
__device__ __forceinline__ int idxK(int row, int d) {
  return row * 128 + ((((d >> 3) ^ row) & 15) << 3) + (d & 7);
}
// Vt: uint [128 d][20] (16 kv-pairs used, stride 20 breaks d*16 bank wrap);
// 16B(4-uint)-chunk swizzle by h(d).
__device__ __forceinline__ int idxVt(int d, int kp) {
  int h = ((d >> 2) ^ ((d & 3) << 1)) & 3;
  return d * 20 + ((((kp >> 2) ^ h) & 3) << 2) + (kp & 3);
}
// Ps: ushort [64 rows][32 cols], 8-ushort-chunk swizzle by quad bits of row.
__device__ __forceinline__ int idxPs(int row, int col) {
  return row * 32 + ((((col >> 3) ^ (row >> 2)) & 3) << 3) + (col & 7);
}

// LDS-only barrier: drains ds ops, leaves global (vmcnt) loads in flight.
__device__ __forceinline__ void barrier_lds() {
  asm volatile("s_waitcnt lgkmcnt(0)\n\ts_barrier" ::: "memory");
}

__global__ __launch_bounds__(256, 2) void attn_ln_mfma(
    const float* __restrict__ qg, const float* __restrict__ kg,
    const float* __restrict__ vg, const float* __restrict__ maskg,
    const float* __restrict__ gammag, const float* __restrict__ betag,
    float* __restrict__ outg)
{
  __shared__ unsigned short KhS[32 * 128];   // 8 KB
  __shared__ unsigned short KlS[32 * 128];   // 8 KB
  __shared__ unsigned int   VtW[128 * 20];   // 10 KB
  __shared__ unsigned short PsS[64 * 32];    // 4 KB
  __shared__ float          lExch[2 * 64];   // khalf x row
  __shared__ float          sExch[2 * 64 * 2]; // dhalf x row x {s1,s2}

  const int tid  = threadIdx.x;
  const int w    = tid >> 6;
  const int lane = tid & 63;
  const int quad = lane >> 4;
  const int lr   = lane & 15;
  const int rowgrp = w & 1;     // q-rows rowgrp*32 .. +32
  const int khalf  = w >> 1;    // QK: k-cols khalf*16..+16; PV: d-cols khalf*64..+64

  // XCD swizzle: blocks on XCD x serve batches {2x,2x+1} -> K/V L2-resident.
  const int id   = blockIdx.x;
  const int xcd  = id & 7;
  const int slot = id >> 3;
  const int b    = xcd * 2 + (slot >> 5);
  const int q0   = (slot & 31) * 64;

  // staging thread maps
  const int c8 = tid & 15, kr = tid >> 4;   // K: d0=c8*8, rows kr+16i
  const int vc = tid & 31, vr = tid >> 5;   // V: d0=vc*4, kp=vr+8j

  const float* gk = kg + (size_t)b * LK_ * D_;
  const float* gv = vg + (size_t)b * LK_ * D_;

  // ---- prefetch tile 0 ----
  float4 kpre[2][2], vpre[2][2];
#pragma unroll
  for (int i = 0; i < 2; i++) {
    const float* p = gk + (size_t)(kr + 16 * i) * D_ + c8 * 8;
    kpre[i][0] = *(const float4*)(p);
    kpre[i][1] = *(const float4*)(p + 4);
  }
#pragma unroll
  for (int j = 0; j < 2; j++) {
    const int kp = vr + 8 * j;
    vpre[j][0] = *(const float4*)(gv + (size_t)(2 * kp) * D_ + vc * 4);
    vpre[j][1] = *(const float4*)(gv + (size_t)(2 * kp + 1) * D_ + vc * 4);
  }

  // ---- Q fragments (hi/lo) for 32 rows (2 rt), registers for whole loop ----
  short8 qh[2][4], ql[2][4];
#pragma unroll
  for (int rt = 0; rt < 2; rt++) {
    const float* qrow = qg + ((size_t)b * LQ_ + q0 + rowgrp * 32 + rt * 16 + lr) * D_ + quad * 8;
#pragma unroll
    for (int c = 0; c < 4; c++) {
      float4 x = *(const float4*)(qrow + c * 32);
      float4 y = *(const float4*)(qrow + c * 32 + 4);
      FragU H, L;
      H.u[0] = pk_bf16(x.x, x.y); H.u[1] = pk_bf16(x.z, x.w);
      H.u[2] = pk_bf16(y.x, y.y); H.u[3] = pk_bf16(y.z, y.w);
      L.u[0] = pk_bf16(x.x - bf_lo(H.u[0]), x.y - bf_hi(H.u[0]));
      L.u[1] = pk_bf16(x.z - bf_lo(H.u[1]), x.w - bf_hi(H.u[1]));
      L.u[2] = pk_bf16(y.x - bf_lo(H.u[2]), y.y - bf_hi(H.u[2]));
      L.u[3] = pk_bf16(y.z - bf_lo(H.u[3]), y.w - bf_hi(H.u[3]));
      qh[rt][c] = H.s8; ql[rt][c] = L.s8;
    }
  }

  float l_part[2][4];
  f32x4 o[2][4];                 // [rt][nb]: d = khalf*64 + nb*16 + lr
  const f32x4 zf = {0.f, 0.f, 0.f, 0.f};
#pragma unroll
  for (int rt = 0; rt < 2; rt++) {
#pragma unroll
    for (int r = 0; r < 4; r++) l_part[rt][r] = 0.f;
#pragma unroll
    for (int n = 0; n < 4; n++) o[rt][n] = zf;
  }

  for (int kt = 0; kt < NTILE; kt++) {
    const int k0 = kt * TK_;
    barrier_lds();   // all waves done with previous tile's LDS (incl. PV reads)

    // ---- stage K (hi/lo bf16), b128 writes ----
#pragma unroll
    for (int i = 0; i < 2; i++) {
      const int row = kr + 16 * i;
      float4 x = kpre[i][0], y = kpre[i][1];
      FragU H, L;
      H.u[0] = pk_bf16(x.x, x.y); H.u[1] = pk_bf16(x.z, x.w);
      H.u[2] = pk_bf16(y.x, y.y); H.u[3] = pk_bf16(y.z, y.w);
      L.u[0] = pk_bf16(x.x - bf_lo(H.u[0]), x.y - bf_hi(H.u[0]));
      L.u[1] = pk_bf16(x.z - bf_lo(H.u[1]), x.w - bf_hi(H.u[1]));
      L.u[2] = pk_bf16(y.x - bf_lo(H.u[2]), y.y - bf_hi(H.u[2]));
      L.u[3] = pk_bf16(y.z - bf_lo(H.u[3]), y.w - bf_hi(H.u[3]));
      const int ik = idxK(row, c8 * 8);
      *(uint4*)&KhS[ik] = H.u4;
      *(uint4*)&KlS[ik] = L.u4;
    }

    // ---- stage V^T as bf16 kv-pairs ----
#pragma unroll
    for (int j = 0; j < 2; j++) {
      const int kp = vr + 8 * j;
      float4 a = vpre[j][0], bb = vpre[j][1];
      VtW[idxVt(vc * 4 + 0, kp)] = pk_bf16(a.x, bb.x);
      VtW[idxVt(vc * 4 + 1, kp)] = pk_bf16(a.y, bb.y);
      VtW[idxVt(vc * 4 + 2, kp)] = pk_bf16(a.z, bb.z);
      VtW[idxVt(vc * 4 + 3, kp)] = pk_bf16(a.w, bb.w);
    }

    // ---- mask loads (this wave's 32 rows x 16 cols) ----
    float mkv[2][4];
#pragma unroll
    for (int rt = 0; rt < 2; rt++)
#pragma unroll
      for (int reg = 0; reg < 4; reg++)
        mkv[rt][reg] = maskg[(size_t)(q0 + rowgrp * 32 + rt * 16 + quad * 4 + reg) * LK_
                             + k0 + khalf * 16 + lr];

    // ---- prefetch NEXT tile (stays in flight across lgkm-only barriers) ----
    if (kt + 1 < NTILE) {
#pragma unroll
      for (int i = 0; i < 2; i++) {
        const float* p = gk + (size_t)(k0 + TK_ + kr + 16 * i) * D_ + c8 * 8;
        kpre[i][0] = *(const float4*)(p);
        kpre[i][1] = *(const float4*)(p + 4);
      }
#pragma unroll
      for (int j = 0; j < 2; j++) {
        const int kp = vr + 8 * j;
        vpre[j][0] = *(const float4*)(gv + (size_t)(k0 + TK_ + 2 * kp) * D_ + vc * 4);
        vpre[j][1] = *(const float4*)(gv + (size_t)(k0 + TK_ + 2 * kp + 1) * D_ + vc * 4);
      }
    }

    barrier_lds();   // staged K/V visible

    // ---- S = Q K^T via MFMA (hi/lo); this wave: 32 rows x 16 k-cols ----
    f32x4 sacc[2];
    sacc[0] = zf; sacc[1] = zf;
#pragma unroll
    for (int c = 0; c < 4; c++) {
      const int kb = c * 32 + quad * 8;
      const int krow = khalf * 16 + lr;
      FragU kh, kl;
      kh.u4 = *(const uint4*)&KhS[idxK(krow, kb)];
      kl.u4 = *(const uint4*)&KlS[idxK(krow, kb)];
#pragma unroll
      for (int rt = 0; rt < 2; rt++) {
        sacc[rt] = __builtin_amdgcn_mfma_f32_16x16x32_bf16(qh[rt][c], kh.s8, sacc[rt], 0, 0, 0);
        sacc[rt] = __builtin_amdgcn_mfma_f32_16x16x32_bf16(ql[rt][c], kh.s8, sacc[rt], 0, 0, 0);
        sacc[rt] = __builtin_amdgcn_mfma_f32_16x16x32_bf16(qh[rt][c], kl.s8, sacc[rt], 0, 0, 0);
      }
    }

    // ---- max-free softmax; P -> shared LDS as bf16 ----
#pragma unroll
    for (int rt = 0; rt < 2; rt++)
#pragma unroll
      for (int reg = 0; reg < 4; reg++) {
        float p = __expf(sacc[rt][reg] + mkv[rt][reg]);
        l_part[rt][reg] += p;
        PsS[idxPs(rowgrp * 32 + rt * 16 + quad * 4 + reg, khalf * 16 + lr)] = bf16_bits(p);
      }

    barrier_lds();   // all waves' Ps visible (PV reads both k-halves)

    // ---- O += P * V via MFMA; this wave: 32 rows x 64 d-cols, full 32 k ----
    FragU Bv[4];
#pragma unroll
    for (int nb = 0; nb < 4; nb++)
      Bv[nb].u4 = *(const uint4*)&VtW[idxVt(khalf * 64 + nb * 16 + lr, quad * 4)];
#pragma unroll
    for (int rt = 0; rt < 2; rt++) {
      FragU A;
      A.u4 = *(const uint4*)&PsS[idxPs(rowgrp * 32 + rt * 16 + lr, quad * 8)];
#pragma unroll
      for (int nb = 0; nb < 4; nb++)
        o[rt][nb] = __builtin_amdgcn_mfma_f32_16x16x32_bf16(A.s8, Bv[nb].s8, o[rt][nb], 0, 0, 0);
    }
  }

  // ---- epilogue ----
  // 1) total l per row: reduce over 16 lanes, exchange k-halves via LDS.
  float lred[2][4];
#pragma unroll
  for (int rt = 0; rt < 2; rt++)
#pragma unroll
    for (int reg = 0; reg < 4; reg++) {
      float l = l_part[rt][reg];
#pragma unroll
      for (int m = 1; m <= 8; m <<= 1) l += __shfl_xor(l, m, 64);
      lred[rt][reg] = l;
    }
  if (lr == 0) {
#pragma unroll
    for (int rt = 0; rt < 2; rt++)
#pragma unroll
      for (int reg = 0; reg < 4; reg++)
        lExch[khalf * 64 + rowgrp * 32 + rt * 16 + quad * 4 + reg] = lred[rt][reg];
  }
  barrier_lds();

  float inv_l[2][4];
#pragma unroll
  for (int rt = 0; rt < 2; rt++)
#pragma unroll
    for (int reg = 0; reg < 4; reg++) {
      const int row = rowgrp * 32 + rt * 16 + quad * 4 + reg;
      inv_l[rt][reg] = 1.f / (lred[rt][reg] + lExch[(1 ^ khalf) * 64 + row]);
    }

  // 2) normalize O, compute partial LN moments over this wave's 64 d-cols.
  float s1p[2][4], s2p[2][4];
#pragma unroll
  for (int rt = 0; rt < 2; rt++)
#pragma unroll
    for (int reg = 0; reg < 4; reg++) {
      float s1 = 0.f, s2 = 0.f;
#pragma unroll
      for (int nb = 0; nb < 4; nb++) {
        float v = o[rt][nb][reg] * inv_l[rt][reg];
        o[rt][nb][reg] = v;
        s1 += v; s2 += v * v;
      }
#pragma unroll
      for (int m = 1; m <= 8; m <<= 1) {
        s1 += __shfl_xor(s1, m, 64);
        s2 += __shfl_xor(s2, m, 64);
      }
      s1p[rt][reg] = s1; s2p[rt][reg] = s2;
    }
  if (lr == 0) {
#pragma unroll
    for (int rt = 0; rt < 2; rt++)
#pragma unroll
      for (int reg = 0; reg < 4; reg++) {
        const int row = rowgrp * 32 + rt * 16 + quad * 4 + reg;
        sExch[(khalf * 64 + row) * 2 + 0] = s1p[rt][reg];
        sExch[(khalf * 64 + row) * 2 + 1] = s2p[rt][reg];
      }
  }
  barrier_lds();

  // 3) gamma/beta for this wave's d-cols, final LN, store.
  float gam[4], bet[4];
#pragma unroll
  for (int nb = 0; nb < 4; nb++) {
    gam[nb] = gammag[khalf * 64 + nb * 16 + lr];
    bet[nb] = betag[khalf * 64 + nb * 16 + lr];
  }

#pragma unroll
  for (int rt = 0; rt < 2; rt++)
#pragma unroll
    for (int reg = 0; reg < 4; reg++) {
      const int row = rowgrp * 32 + rt * 16 + quad * 4 + reg;
      const float s1 = s1p[rt][reg] + sExch[((1 ^ khalf) * 64 + row) * 2 + 0];
      const float s2 = s2p[rt][reg] + sExch[((1 ^ khalf) * 64 + row) * 2 + 1];
      const float mean = s1 * (1.f / 128.f);
      const float var  = s2 * (1.f / 128.f) - mean * mean;
      const float rstd = rsqrtf(var + LN_EPS);

      float* op = outg + ((size_t)b * LQ_ + q0 + row) * D_ + khalf * 64 + lr;
#pragma unroll
      for (int nb = 0; nb < 4; nb++)
        op[nb * 16] = (o[rt][nb][reg] - mean) * rstd * gam[nb] + bet[nb];
    }
}

extern "C" void kernel_launch(void* const* d_in, const int* in_sizes, int n_in,
                              void* d_out, int out_size, void* d_ws, size_t ws_size,
                              hipStream_t stream) {
  const float* q     = (const float*)d_in[0];
  const float* k     = (const float*)d_in[1];
  const float* v     = (const float*)d_in[2];
  const float* mask  = (const float*)d_in[3];
  const float* gamma = (const float*)d_in[4];
  const float* beta  = (const float*)d_in[5];
  float* out = (float*)d_out;

  attn_ln_mfma<<<dim3(512), dim3(256), 0, stream>>>(q, k, v, mask, gamma, beta, out);
}